// Round 13
// baseline (154.263 us; speedup 1.0000x reference)
//
#include <hip/hip_runtime.h>
#include <hip/hip_bf16.h>

typedef __bf16 bf16_t;
typedef __bf16 bf16x8 __attribute__((ext_vector_type(8)));
typedef float f32x4 __attribute__((ext_vector_type(4)));
typedef __fp16 f16x2 __attribute__((ext_vector_type(2)));

#define BATCH 4
#define SEQ 4096
#define FIN 33
#define DIM 64
#define LOG2E 1.4426950408889634f

__device__ __forceinline__ float dexp2(float x) { return __builtin_amdgcn_exp2f(x); }
__device__ __forceinline__ unsigned pk(float a, float b)
{ return __builtin_bit_cast(unsigned, __builtin_amdgcn_cvt_pkrtz(a, b)); }
__device__ __forceinline__ f16x2 uph(unsigned u)
{ return __builtin_bit_cast(f16x2, u); }
__device__ __forceinline__ float f16lo(unsigned u)
{ return (float)uph(u)[0]; }

__device__ __forceinline__ f32x4 mm2(bf16x8 a0, bf16x8 a1, bf16x8 b0, bf16x8 b1)
{
    f32x4 acc = {0.f, 0.f, 0.f, 0.f};
    acc = __builtin_amdgcn_mfma_f32_16x16x32_bf16(a0, b0, acc, 0, 0, 0);
    acc = __builtin_amdgcn_mfma_f32_16x16x32_bf16(a1, b1, acc, 0, 0, 0);
    return acc;
}

// ---------------- Kernel 1: q/k affine projections ----------------
__global__ __launch_bounds__(256) void qk_proj_kernel(
    const float* __restrict__ x, const float* __restrict__ Wq,
    const float* __restrict__ bq, const float* __restrict__ Wk,
    const float* __restrict__ bk,
    bf16_t* __restrict__ qout, bf16_t* __restrict__ kout)
{
    __shared__ float sWq[FIN * DIM];
    __shared__ float sWk[FIN * DIM];
    __shared__ float sb[2 * DIM];
    const int t = threadIdx.x;
    for (int i = t; i < FIN * DIM; i += 256) { sWq[i] = Wq[i]; sWk[i] = Wk[i]; }
    if (t < DIM) { sb[t] = bq[t]; sb[DIM + t] = bk[t]; }
    __syncthreads();

    const int row = blockIdx.x * 4 + (t >> 6);
    const int d   = t & 63;
    const float* xr = x + (size_t)row * FIN;
    float qacc = sb[d], kacc = sb[DIM + d];
#pragma unroll
    for (int f = 0; f < FIN; ++f) {
        const float xv = xr[f];
        qacc += xv * sWq[f * DIM + d];
        kacc += xv * sWk[f * DIM + d];
    }
    qout[(size_t)row * DIM + d] = (bf16_t)qacc;
    kout[(size_t)row * DIM + d] = (bf16_t)kacc;
}

#define LDK(ct, h) (*reinterpret_cast<const bf16x8*>(kw + (size_t)(ct) * 16 * DIM + (h) * 32))

// ---------------- Kernel 2: M and Z (two sweeps, no stores-before-loads) ----------------
// 512 WGs x 256 thr. WG = 32 rows (two 16-row MFMA blocks, shared k tiles).
// Wave w covers cols [w*1024, +1024) = 64 tiles. Writes cM = log2e/M, invZ = 1/Z.
__global__ __launch_bounds__(256) void mz_kernel(
    const bf16_t* __restrict__ qg, const bf16_t* __restrict__ kg,
    float* __restrict__ cMg, float* __restrict__ invZg)
{
    const int wg   = blockIdx.x;        // rows wg*32 .. +32 (never straddles a batch)
    const int b    = wg >> 7;           // batch
    const int t    = threadIdx.x;
    const int w    = t >> 6;            // wave 0..3
    const int l    = t & 63;
    const int lr   = l & 15;
    const int kg4  = l >> 4;
    const int col0 = w << 10;           // 1024 cols per wave

    const bf16_t* kw = kg + ((size_t)b * SEQ + col0 + lr) * DIM + kg4 * 8;
    const bf16_t* qb = qg + (size_t)(wg * 32) * DIM;

    const bf16x8 qa0 = *reinterpret_cast<const bf16x8*>(qb + lr * DIM + kg4 * 8);
    const bf16x8 qa1 = *reinterpret_cast<const bf16x8*>(qb + lr * DIM + 32 + kg4 * 8);
    const bf16x8 qb0 = *reinterpret_cast<const bf16x8*>(qb + (16 + lr) * DIM + kg4 * 8);
    const bf16x8 qb1 = *reinterpret_cast<const bf16x8*>(qb + (16 + lr) * DIM + 32 + kg4 * 8);

    __shared__ float redM[4][32];
    __shared__ float redZ[4][32];

    // ---- sweep 1: row max for both 16-row blocks ----
    float vA[4] = {-3.4e38f, -3.4e38f, -3.4e38f, -3.4e38f};
    float vB[4] = {-3.4e38f, -3.4e38f, -3.4e38f, -3.4e38f};
    {
        bf16x8 p0a = LDK(0, 0), p0b = LDK(0, 1);
        bf16x8 p1a = LDK(1, 0), p1b = LDK(1, 1);
#pragma unroll 4
        for (int ct = 0; ct < 64; ct += 2) {
            f32x4 aA = mm2(qa0, qa1, p0a, p0b);
            f32x4 aB = mm2(qb0, qb1, p0a, p0b);
            if (ct + 2 < 64) { p0a = LDK(ct + 2, 0); p0b = LDK(ct + 2, 1); }
#pragma unroll
            for (int j = 0; j < 4; ++j) { vA[j] = fmaxf(vA[j], aA[j]); vB[j] = fmaxf(vB[j], aB[j]); }
            f32x4 cA = mm2(qa0, qa1, p1a, p1b);
            f32x4 cB = mm2(qb0, qb1, p1a, p1b);
            if (ct + 3 < 64) { p1a = LDK(ct + 3, 0); p1b = LDK(ct + 3, 1); }
#pragma unroll
            for (int j = 0; j < 4; ++j) { vA[j] = fmaxf(vA[j], cA[j]); vB[j] = fmaxf(vB[j], cB[j]); }
        }
    }
#pragma unroll
    for (int m = 1; m < 16; m <<= 1) {
#pragma unroll
        for (int j = 0; j < 4; ++j) {
            vA[j] = fmaxf(vA[j], __shfl_xor(vA[j], m, 64));
            vB[j] = fmaxf(vB[j], __shfl_xor(vB[j], m, 64));
        }
    }
    if (lr == 0) {
#pragma unroll
        for (int j = 0; j < 4; ++j) {
            redM[w][kg4 * 4 + j]      = vA[j];
            redM[w][16 + kg4 * 4 + j] = vB[j];
        }
    }
    __syncthreads();
    float cMA[4], cMB[4];
#pragma unroll
    for (int j = 0; j < 4; ++j) {
        const int rA = kg4 * 4 + j, rB = 16 + kg4 * 4 + j;
        float mA = redM[0][rA], mB = redM[0][rB];
#pragma unroll
        for (int ww = 1; ww < 4; ++ww) { mA = fmaxf(mA, redM[ww][rA]); mB = fmaxf(mB, redM[ww][rB]); }
        cMA[j] = LOG2E / mA;
        cMB[j] = LOG2E / mB;
    }

    // ---- sweep 2: Z = sum 2^(s*cM - log2e) ----
    float zA[4] = {0.f, 0.f, 0.f, 0.f};
    float zB[4] = {0.f, 0.f, 0.f, 0.f};
    {
        bf16x8 p0a = LDK(0, 0), p0b = LDK(0, 1);
        bf16x8 p1a = LDK(1, 0), p1b = LDK(1, 1);
#pragma unroll 4
        for (int ct = 0; ct < 64; ct += 2) {
            f32x4 aA = mm2(qa0, qa1, p0a, p0b);
            f32x4 aB = mm2(qb0, qb1, p0a, p0b);
            if (ct + 2 < 64) { p0a = LDK(ct + 2, 0); p0b = LDK(ct + 2, 1); }
#pragma unroll
            for (int j = 0; j < 4; ++j) {
                zA[j] += dexp2(fmaf(aA[j], cMA[j], -LOG2E));
                zB[j] += dexp2(fmaf(aB[j], cMB[j], -LOG2E));
            }
            f32x4 cA = mm2(qa0, qa1, p1a, p1b);
            f32x4 cB = mm2(qb0, qb1, p1a, p1b);
            if (ct + 3 < 64) { p1a = LDK(ct + 3, 0); p1b = LDK(ct + 3, 1); }
#pragma unroll
            for (int j = 0; j < 4; ++j) {
                zA[j] += dexp2(fmaf(cA[j], cMA[j], -LOG2E));
                zB[j] += dexp2(fmaf(cB[j], cMB[j], -LOG2E));
            }
        }
    }
#pragma unroll
    for (int m = 1; m < 16; m <<= 1) {
#pragma unroll
        for (int j = 0; j < 4; ++j) {
            zA[j] += __shfl_xor(zA[j], m, 64);
            zB[j] += __shfl_xor(zB[j], m, 64);
        }
    }
    if (lr == 0) {
#pragma unroll
        for (int j = 0; j < 4; ++j) {
            redZ[w][kg4 * 4 + j]      = zA[j];
            redZ[w][16 + kg4 * 4 + j] = zB[j];
        }
    }
    __syncthreads();
    if (t < 32) {
        float mm = redM[0][t], zz = redZ[0][t];
#pragma unroll
        for (int ww = 1; ww < 4; ++ww) { mm = fmaxf(mm, redM[ww][t]); zz += redZ[ww][t]; }
        cMg[wg * 32 + t]   = LOG2E / mm;
        invZg[wg * 32 + t] = 1.0f / zz;
    }
}

// ---------------- Kernel 3: recompute + exp + full-line store (barrier-free) ----------------
// 4096 WGs x 256 thr. Each wave = one (16-row block, 256-col chunk), fully
// independent: all loads precede all stores (no vmcnt coupling), e bounced
// through a wave-private 8 KB LDS slice for 128B full-line stores.
__global__ __launch_bounds__(256) void p_kernel(
    const bf16_t* __restrict__ qg, const bf16_t* __restrict__ kg,
    const float* __restrict__ cMg, const float* __restrict__ invZg,
    float* __restrict__ out)
{
    const int w     = threadIdx.x >> 6;           // wave 0..3
    const int chunk = blockIdx.x * 4 + w;         // 0..16383
    const int rb    = chunk >> 4;                 // row-block 0..1023
    const int cc    = chunk & 15;                 // col-chunk 0..15
    const int b     = rb >> 8;                    // batch
    const int l     = threadIdx.x & 63;
    const int lr    = l & 15;
    const int kg4   = l >> 4;
    const int col0  = cc << 8;
    const int sr    = l >> 3;                     // store-pass row 0..7

    __shared__ uint2 sS[4][4][256];               // [wave][row-group][col]
    uint2* const sp = &sS[w][kg4][lr];

    // per-row constants (issued first; L2-hot)
    float cM[4];
#pragma unroll
    for (int j = 0; j < 4; ++j) cM[j] = cMg[rb * 16 + kg4 * 4 + j];
    const float iz0 = invZg[rb * 16 + sr];
    const float iz1 = invZg[rb * 16 + sr + 8];

    const bf16_t* qb = qg + (size_t)(rb * 16) * DIM;
    const bf16x8 a0 = *reinterpret_cast<const bf16x8*>(qb + lr * DIM + kg4 * 8);
    const bf16x8 a1 = *reinterpret_cast<const bf16x8*>(qb + lr * DIM + 32 + kg4 * 8);
    const bf16_t* kw = kg + ((size_t)b * SEQ + col0 + lr) * DIM + kg4 * 8;

    // ---- sweep: k loads + MFMA + exp + pack -> LDS (no global stores yet) ----
    {
        bf16x8 p0a = LDK(0, 0), p0b = LDK(0, 1);
        bf16x8 p1a = LDK(1, 0), p1b = LDK(1, 1);
#pragma unroll
        for (int ct = 0; ct < 16; ct += 2) {
            f32x4 acc0 = mm2(a0, a1, p0a, p0b);
            if (ct + 2 < 16) { p0a = LDK(ct + 2, 0); p0b = LDK(ct + 2, 1); }
            {
                const float e0 = dexp2(fmaf(acc0[0], cM[0], -LOG2E));
                const float e1 = dexp2(fmaf(acc0[1], cM[1], -LOG2E));
                const float e2 = dexp2(fmaf(acc0[2], cM[2], -LOG2E));
                const float e3 = dexp2(fmaf(acc0[3], cM[3], -LOG2E));
                sp[ct * 16] = make_uint2(pk(e0, e1), pk(e2, e3));
            }
            f32x4 acc1 = mm2(a0, a1, p1a, p1b);
            if (ct + 3 < 16) { p1a = LDK(ct + 3, 0); p1b = LDK(ct + 3, 1); }
            {
                const float e0 = dexp2(fmaf(acc1[0], cM[0], -LOG2E));
                const float e1 = dexp2(fmaf(acc1[1], cM[1], -LOG2E));
                const float e2 = dexp2(fmaf(acc1[2], cM[2], -LOG2E));
                const float e3 = dexp2(fmaf(acc1[3], cM[3], -LOG2E));
                sp[(ct + 1) * 16] = make_uint2(pk(e0, e1), pk(e2, e3));
            }
        }
    }
    asm volatile("s_waitcnt lgkmcnt(0)" ::: "memory");  // e visible to whole wave

    // ---- store pass: 128B full-line dwordx4 stores ----
    {
        const int  cl  = (l & 7) * 4;
        const unsigned hsh = (unsigned)((sr & 1) * 16);
        const bool hiw = (sr & 2) != 0;
        const int  g0  = sr >> 2;
        float* ob0 = out + ((size_t)(rb * 16 + sr)) * SEQ + col0;
        float* ob1 = ob0 + (size_t)8 * SEQ;
#pragma unroll
        for (int it = 0; it < 8; ++it) {
            const int c = it * 32 + cl;
            const uint4 A0 = *reinterpret_cast<const uint4*>(&sS[w][g0][c]);
            const uint4 B0 = *reinterpret_cast<const uint4*>(&sS[w][g0][c + 2]);
            const uint4 A1 = *reinterpret_cast<const uint4*>(&sS[w][g0 + 2][c]);
            const uint4 B1 = *reinterpret_cast<const uint4*>(&sS[w][g0 + 2][c + 2]);
            f32x4 v0, v1;
            v0[0] = f16lo((hiw ? A0.y : A0.x) >> hsh);
            v0[1] = f16lo((hiw ? A0.w : A0.z) >> hsh);
            v0[2] = f16lo((hiw ? B0.y : B0.x) >> hsh);
            v0[3] = f16lo((hiw ? B0.w : B0.z) >> hsh);
            v1[0] = f16lo((hiw ? A1.y : A1.x) >> hsh);
            v1[1] = f16lo((hiw ? A1.w : A1.z) >> hsh);
            v1[2] = f16lo((hiw ? B1.y : B1.x) >> hsh);
            v1[3] = f16lo((hiw ? B1.w : B1.z) >> hsh);
            *reinterpret_cast<f32x4*>(ob0 + c) = v0 * iz0;
            *reinterpret_cast<f32x4*>(ob1 + c) = v1 * iz1;
        }
    }
}

extern "C" void kernel_launch(void* const* d_in, const int* in_sizes, int n_in,
                              void* d_out, int out_size, void* d_ws, size_t ws_size,
                              hipStream_t stream)
{
    const float* x  = (const float*)d_in[0];
    const float* Wq = (const float*)d_in[1];
    const float* bq = (const float*)d_in[2];
    const float* Wk = (const float*)d_in[3];
    const float* bk = (const float*)d_in[4];
    float* out = (float*)d_out;

    bf16_t* qws = (bf16_t*)d_ws;
    bf16_t* kws = qws + (size_t)BATCH * SEQ * DIM;
    float*  cMg = (float*)(kws + (size_t)BATCH * SEQ * DIM);
    float*  iZg = cMg + (size_t)BATCH * SEQ;

    qk_proj_kernel<<<(BATCH * SEQ) / 4, 256, 0, stream>>>(x, Wq, bq, Wk, bk, qws, kws);
    mz_kernel<<<BATCH * (SEQ / 32), 256, 0, stream>>>(qws, kws, cMg, iZg);
    p_kernel<<<BATCH * (SEQ / 16) * 16 / 4, 256, 0, stream>>>(qws, kws, cMg, iZg, out);
}